// Round 12
// baseline (554.021 us; speedup 1.0000x reference)
//
#include <hip/hip_runtime.h>

// Round 12 = Round 11 + per-SIMD wave stagger + setprio.
// Diagnosis r11: phase = MFMA section (1552 cyc/SIMD) + VALU section (1650)
// SERIALIZED because both waves per SIMD issue MMX-then-GATEC in lockstep.
// Fix: waves 0-3 run {MMX; GATE}, waves 4-7 run {GATE; MMX} (SIMD s hosts
// waves s and s+4) -> every SIMD has one MFMA-issuing and one VALU-issuing
// wave at all times; s_setprio(1) wraps MMX to keep the MFMA wave favored.
// No schedule/race change: within every phase MMX reads and GATEC writes
// disjoint hL chunks; POSC reads a chunk that is read-only in that phase.
// Everything else identical to r11 (4-bit swizzle, prescaled weights, K=32
// obs/bias MFMA fold, decoder pos-fold, c in f32 regs, 2 waves/SIMD).

#define OBS_LEN 8
#define PRED_LEN 12
#define BATCH 131072
#define HID 128
#define NZ 512
#define KWT 128
#define XK 32
#define A2S 40          // A2 row stride (u16): 80B -> 2-way banks (free)

typedef float f32x4 __attribute__((ext_vector_type(4)));
typedef float f32x2 __attribute__((ext_vector_type(2)));
typedef unsigned short u16x8 __attribute__((ext_vector_type(8)));
typedef __bf16 bf16x8 __attribute__((ext_vector_type(8)));

#define K2F 1.4426950408889634f   // log2(e)

static __device__ __forceinline__ unsigned short cvt1(float f) {
  __bf16 b = (__bf16)f;
  return __builtin_bit_cast(unsigned short, b);
}
static __device__ __forceinline__ float bf2f(unsigned short h) {
  return __uint_as_float(((unsigned int)h) << 16);
}

// ---------------- prep (r10-verified, unchanged) ----------------
// Permuted col c: cg=c>>6, gate=(c>>4)&3, cl=c&15; unit=cg*16+cl; n=gate*128+unit.
// Scale s = -2*log2e for gate g (index 2), else -log2e.
__global__ void prep_weights(const float* __restrict__ We,   const float* __restrict__ be,
                             const float* __restrict__ Wih_e,const float* __restrict__ Whh_e,
                             const float* __restrict__ b_e,
                             const float* __restrict__ Wd,   const float* __restrict__ bd,
                             const float* __restrict__ Wih_d,const float* __restrict__ Whh_d,
                             const float* __restrict__ b_d,
                             const float* __restrict__ Wo,   const float* __restrict__ bo,
                             unsigned short* __restrict__ wt_enc,
                             unsigned short* __restrict__ wt_dec,
                             unsigned short* __restrict__ xw_enc,
                             unsigned short* __restrict__ xw_dec) {
  const int c = blockIdx.x & (NZ - 1);
  const bool dec = blockIdx.x >= NZ;
  const int cg = c >> 6, gate = (c >> 4) & 3, cl = c & 15;
  const int unit = cg * 16 + cl;
  const int n = gate * HID + unit;
  const float s = (gate == 2) ? (-2.f * K2F) : (-K2F);

  const float* Whh = dec ? Whh_d : Whh_e;
  const float* Wih = dec ? Wih_d : Wih_e;
  const float* Wem = dec ? Wd : We;
  const float* bem = dec ? bd : be;
  const float* bl  = dec ? b_d : b_e;
  unsigned short* wt = dec ? wt_dec : wt_enc;
  unsigned short* xw = dec ? xw_dec : xw_enc;

  float wx = 0.f, wy = 0.f;
  for (int e = 0; e < HID; ++e) {
    wx += Wem[e] * Wih[e * NZ + n];
    wy += Wem[HID + e] * Wih[e * NZ + n];
  }
  for (int k = threadIdx.x; k < KWT; k += 64) {
    float v = Whh[k * NZ + n];
    if (dec) v += Wo[k * 2] * wx + Wo[k * 2 + 1] * wy;
    wt[c * KWT + k] = cvt1(s * v);
  }
  if (threadIdx.x == 0) {
    float bb = bl[n];
    for (int e = 0; e < HID; ++e) bb += bem[e] * Wih[e * NZ + n];
    if (dec) bb += bo[0] * wx + bo[1] * wy;
    unsigned short* xr = xw + c * XK;
    for (int k = 5; k < XK; ++k) xr[k] = 0;
    if (dec) {
      xr[0] = 0; xr[1] = 0; xr[2] = cvt1(s * bb); xr[3] = 0; xr[4] = 0;
    } else {
      xr[0] = cvt1(s * wx); xr[1] = cvt1(s * wy); xr[2] = cvt1(s * bb);
      xr[3] = xr[0]; xr[4] = xr[1];
    }
  }
}

// ---------------- main fused kernel ----------------
// MFMA 16x16x32 bf16 (HW-verified r1-r11):
//  A/B frag: row/col = lane&15, k = 32kc + (lane>>4)*8 + j
//  C/D: col = lane&15, row = (lane>>4)*4 + reg
// hL swizzle (4-bit, bijective): elem(r,k) = r*128 + (((k>>3)^(r&15))<<3)+(k&7)

#define MFMA(A, B, C)                                                          \
  __builtin_amdgcn_mfma_f32_16x16x32_bf16(                                     \
      __builtin_bit_cast(bf16x8, (A)), __builtin_bit_cast(bf16x8, (B)), (C),   \
      0, 0, 0)

#define EXP4(D, S)                                                             \
  { f32x4 _s = (S);                                                            \
    D[0] = __builtin_amdgcn_exp2f(_s[0]); D[1] = __builtin_amdgcn_exp2f(_s[1]);\
    D[2] = __builtin_amdgcn_exp2f(_s[2]); D[3] = __builtin_amdgcn_exp2f(_s[3]); }
#define RCP4(D, S)                                                             \
  { f32x4 _r = (S);                                                            \
    D[0] = __builtin_amdgcn_rcpf(_r[0]); D[1] = __builtin_amdgcn_rcpf(_r[1]);  \
    D[2] = __builtin_amdgcn_rcpf(_r[2]); D[3] = __builtin_amdgcn_rcpf(_r[3]); }

#define LOADW(WT, XW)                                                          \
  { _Pragma("unroll")                                                          \
    for (int kc = 0; kc < 4; ++kc) {                                           \
      _Pragma("unroll")                                                        \
      for (int g = 0; g < 4; ++g)                                              \
        bfr[kc][g] =                                                           \
            *(const u16x8*)&(WT)[(cg * 64 + g * 16 + l15) * KWT + kc * 32 +    \
                                 l4 * 8];                                      \
    }                                                                          \
    _Pragma("unroll")                                                          \
    for (int g = 0; g < 4; ++g)                                                \
      xfr[g] = *(const u16x8*)&(XW)[(cg * 64 + g * 16 + l15) * XK + l4 * 8]; }

// full matmul for chunk X: x-block (K=32, zero-C) then h (K=128).
#define MMX(ACC, X)                                                            \
  { u16x8 mm_a2a = *(const u16x8*)&A2[(X)*32 * A2S + l15 * A2S + l4 * 8];      \
    u16x8 mm_a2b =                                                             \
        *(const u16x8*)&A2[(X)*32 * A2S + (16 + l15) * A2S + l4 * 8];          \
    _Pragma("unroll")                                                          \
    for (int g = 0; g < 4; ++g) {                                              \
      ACC[0][g] = MFMA(mm_a2a, xfr[g], ZROV);                                  \
      ACC[1][g] = MFMA(mm_a2b, xfr[g], ZROV);                                  \
    }                                                                          \
    _Pragma("unroll")                                                          \
    for (int kc = 0; kc < 4; ++kc) {                                           \
      const int mm_g = (((kc * 4 + l4) ^ l15) << 3);                           \
      u16x8 mm_a0 = *(const u16x8*)&hL[(X)*4096 + l15 * 128 + mm_g];           \
      u16x8 mm_a1 = *(const u16x8*)&hL[(X)*4096 + (16 + l15) * 128 + mm_g];    \
      _Pragma("unroll")                                                        \
      for (int g = 0; g < 4; ++g) {                                            \
        ACC[0][g] = MFMA(mm_a0, bfr[kc][g], ACC[0][g]);                        \
        ACC[1][g] = MFMA(mm_a1, bfr[kc][g], ACC[1][g]);                        \
      } } }

// gate for chunk X: acc already = scaled z (incl obs fold + bias)
#define GATEC(ACC, CRR, X)                                                     \
  { _Pragma("unroll")                                                          \
    for (int m = 0; m < 2; ++m) {                                              \
      f32x4 g_eB, g_eA, g_eG, g_eO;                                            \
      EXP4(g_eB, ACC[m][0]) EXP4(g_eA, ACC[m][1])                              \
      EXP4(g_eG, ACC[m][2]) EXP4(g_eO, ACC[m][3])                              \
      f32x4 g_a1 = 1.f + g_eA, g_b1 = 1.f + g_eB, g_g1 = 1.f + g_eG;           \
      f32x4 g_bg = g_b1 * g_g1;                                                \
      f32x4 g_rd; RCP4(g_rd, g_a1 * g_bg)                                      \
      f32x4 g_cv = (CRR[m] * g_bg + (1.f - g_eG) * g_a1) * g_rd;               \
      CRR[m] = g_cv;                                                           \
      f32x4 g_eC; EXP4(g_eC, g_cv * (-2.f * K2F))                              \
      f32x4 g_rh; RCP4(g_rh, (1.f + g_eO) * (1.f + g_eC))                      \
      f32x4 g_hv = (1.f - g_eC) * g_rh;                                        \
      const int g_R0 = 16 * m + l4 * 4;                                        \
      _Pragma("unroll")                                                        \
      for (int r = 0; r < 4; ++r)                                              \
        hL[(X)*4096 + (g_R0 + r) * 128 +                                       \
           ((uh ^ ((g_R0 + r) & 15)) << 3) + ul] = cvt1(g_hv[r]);              \
    } }

// pos = h @ Wo + bo, fire-and-forget. 16 thr/row over 32 rows of chunk X.
#define POSC(S, X)                                                             \
  { const int pp_r = tid >> 4, pp_q = tid & 15;                                \
    u16x8 pp_h = *(const u16x8*)&hL[(X)*4096 + pp_r * 128 +                    \
                                    ((pp_q ^ (pp_r & 15)) << 3)];              \
    const float* pp_w = WoL + pp_q * 16;                                       \
    f32x4 pp_w0 = *(const f32x4*)pp_w;                                         \
    f32x4 pp_w1 = *(const f32x4*)(pp_w + 4);                                   \
    f32x4 pp_w2 = *(const f32x4*)(pp_w + 8);                                   \
    f32x4 pp_w3 = *(const f32x4*)(pp_w + 12);                                  \
    f32x2 pp_s = (f32x2){0.f, 0.f};                                            \
    pp_s += bf2f(pp_h[0]) * (f32x2){pp_w0[0], pp_w0[1]};                       \
    pp_s += bf2f(pp_h[1]) * (f32x2){pp_w0[2], pp_w0[3]};                       \
    pp_s += bf2f(pp_h[2]) * (f32x2){pp_w1[0], pp_w1[1]};                       \
    pp_s += bf2f(pp_h[3]) * (f32x2){pp_w1[2], pp_w1[3]};                       \
    pp_s += bf2f(pp_h[4]) * (f32x2){pp_w2[0], pp_w2[1]};                       \
    pp_s += bf2f(pp_h[5]) * (f32x2){pp_w2[2], pp_w2[3]};                       \
    pp_s += bf2f(pp_h[6]) * (f32x2){pp_w3[0], pp_w3[1]};                       \
    pp_s += bf2f(pp_h[7]) * (f32x2){pp_w3[2], pp_w3[3]};                       \
    pp_s[0] += __shfl_xor(pp_s[0], 1); pp_s[1] += __shfl_xor(pp_s[1], 1);      \
    pp_s[0] += __shfl_xor(pp_s[0], 2); pp_s[1] += __shfl_xor(pp_s[1], 2);      \
    pp_s[0] += __shfl_xor(pp_s[0], 4); pp_s[1] += __shfl_xor(pp_s[1], 4);      \
    pp_s[0] += __shfl_xor(pp_s[0], 8); pp_s[1] += __shfl_xor(pp_s[1], 8);      \
    if (pp_q == 0) {                                                           \
      float2 pp_o; pp_o.x = pp_s[0] + bo0; pp_o.y = pp_s[1] + bo1;             \
      ((float2*)out)[(size_t)(S)*BATCH + row0 + (X)*32 + pp_r] = pp_o;         \
    } }

// stage encoder A2 for chunk X, step T (exact hi/lo split)
#define STAGE_OBS_A2(T, X)                                                     \
  if (tid < 32) {                                                              \
    float2 so_p =                                                              \
        ((const float2*)obs)[(size_t)(T)*BATCH + row0 + (X)*32 + tid];         \
    unsigned short so_x = cvt1(so_p.x), so_y = cvt1(so_p.y);                   \
    unsigned short* so_r = &A2[(X)*32 * A2S + tid * A2S];                      \
    so_r[0] = so_x; so_r[1] = so_y; so_r[2] = 0x3F80u;                         \
    so_r[3] = cvt1(so_p.x - bf2f(so_x));                                       \
    so_r[4] = cvt1(so_p.y - bf2f(so_y));                                       \
  }

// decoder A2 constants for chunk X
#define STAGE_DEC_A2(X)                                                        \
  if (tid < 32) {                                                              \
    unsigned short* sd_r = &A2[(X)*32 * A2S + tid * A2S];                      \
    sd_r[0] = 0; sd_r[1] = 0; sd_r[2] = 0x3F80u; sd_r[3] = 0; sd_r[4] = 0;     \
  }

// staggered phase: waves 0-3 do {MM; GATE}, waves 4-7 do {GATE; MM}.
// SIMD s hosts waves s and s+4 -> one MFMA wave + one VALU wave per SIMD.
#define PHASE(MM, GATE)                                                        \
  {                                                                            \
    if (wlo) {                                                                 \
      __builtin_amdgcn_s_setprio(1);                                           \
      MM                                                                       \
      __builtin_amdgcn_s_setprio(0);                                           \
      GATE                                                                     \
    } else {                                                                   \
      GATE                                                                     \
      __builtin_amdgcn_s_setprio(1);                                           \
      MM                                                                       \
      __builtin_amdgcn_s_setprio(0);                                           \
    }                                                                          \
  }                                                                            \
  __syncthreads();

__global__ __launch_bounds__(512, 2) void lstm_fused(
    const float* __restrict__ obs,
    const unsigned short* __restrict__ wt_enc,
    const unsigned short* __restrict__ wt_dec,
    const unsigned short* __restrict__ xw_enc,
    const unsigned short* __restrict__ xw_dec,
    const float* __restrict__ Wo, const float* __restrict__ bo,
    float* __restrict__ out) {
  __shared__ unsigned short hL[2 * 32 * 128];   // 16 KB, 4-bit XOR-swizzled
  __shared__ unsigned short A2[2 * 32 * A2S];   // 5 KB
  __shared__ float WoL[HID * 2];                // 1 KB

  const int tid = threadIdx.x;
  const int lane = tid & 63;
  const int cg = tid >> 6;          // wave 0..7 -> cols [64cg, 64cg+64)
  const bool wlo = cg < 4;          // wave s and s+4 share SIMD s
  const int l15 = lane & 15;
  const int l4 = lane >> 4;
  const int row0 = blockIdx.x * 64;
  const int u = cg * 16 + l15, uh = u >> 3, ul = u & 7;
  const float bo0 = bo[0], bo1 = bo[1];
  const f32x4 ZROV = {0.f, 0.f, 0.f, 0.f};

  // ---- P0a: zero hL + A2, load WoL + weights ----
  {
    u16x8 z8 = (u16x8){0, 0, 0, 0, 0, 0, 0, 0};
    *(u16x8*)&hL[tid * 8] = z8;                      // 512*8 = 4096
    *(u16x8*)&hL[4096 + tid * 8] = z8;
    unsigned short* az = &A2[tid * 5];               // 512*5 = 2560 = 2*32*40
    az[0] = 0; az[1] = 0; az[2] = 0; az[3] = 0; az[4] = 0;
  }
  if (tid < HID) { WoL[tid * 2] = Wo[tid * 2]; WoL[tid * 2 + 1] = Wo[tid * 2 + 1]; }

  u16x8 bfr[4][4], xfr[4];          // persistent weights: 80 regs
  LOADW(wt_enc, xw_enc);

  f32x4 accA[2][4], accB[2][4];
  f32x4 crrA[2], crrB[2];
  crrA[0] = crrA[1] = ZROV;
  crrB[0] = crrB[1] = ZROV;
  __syncthreads();

  // ---- P0b: stage A2_A(0). (A2_B(0) is staged in alpha(0).) ----
  STAGE_OBS_A2(0, 0)
  __syncthreads();

  // ---- encoder t = 0..7 ----
#pragma unroll 1
  for (int t = 0; t < OBS_LEN; ++t) {
    PHASE(MMX(accA, 0),
          { if (t > 0) { GATEC(accB, crrB, 1) } STAGE_OBS_A2(t, 1) })
    PHASE(MMX(accB, 1),
          { GATEC(accA, crrA, 0)
            if (t + 1 < OBS_LEN) { STAGE_OBS_A2(t + 1, 0) }
            else { STAGE_DEC_A2(0) } })
  }

  // ---- transition: decoder weights; reset c for chunk A ----
  LOADW(wt_dec, xw_dec);
  crrA[0] = crrA[1] = ZROV;

  // alpha_d(1): MM_A^dec(1) || GATE_B(7,enc) + POSC_A(0) + stage A2_B dec
  PHASE(MMX(accA, 0),
        { GATEC(accB, crrB, 1) POSC(0, 0) STAGE_DEC_A2(1) })
  crrB[0] = crrB[1] = ZROV;

  // beta_d(1): MM_B^dec(1) || GATE_A^dec(1) + POSC_B(0)
  PHASE(MMX(accB, 1), { GATEC(accA, crrA, 0) POSC(0, 1) })

  // ---- decoder d = 2..11 ----
#pragma unroll 1
  for (int d = 2; d < PRED_LEN; ++d) {
    PHASE(MMX(accA, 0), { GATEC(accB, crrB, 1) POSC(d - 1, 0) })
    PHASE(MMX(accB, 1), { GATEC(accA, crrA, 0) POSC(d - 1, 1) })
  }

  // ---- epilogue ----
  GATEC(accB, crrB, 1)
  POSC(PRED_LEN - 1, 0)
  __syncthreads();
  POSC(PRED_LEN - 1, 1)
}

extern "C" void kernel_launch(void* const* d_in, const int* in_sizes, int n_in,
                              void* d_out, int out_size, void* d_ws, size_t ws_size,
                              hipStream_t stream) {
  const float* obs   = (const float*)d_in[0];
  const float* We    = (const float*)d_in[1];
  const float* be    = (const float*)d_in[2];
  const float* Wih_e = (const float*)d_in[3];
  const float* Whh_e = (const float*)d_in[4];
  const float* b_e   = (const float*)d_in[5];
  const float* Wd    = (const float*)d_in[6];
  const float* bd    = (const float*)d_in[7];
  const float* Wih_d = (const float*)d_in[8];
  const float* Whh_d = (const float*)d_in[9];
  const float* b_d   = (const float*)d_in[10];
  const float* Wo    = (const float*)d_in[11];
  const float* bo    = (const float*)d_in[12];
  float* out = (float*)d_out;

  unsigned short* wt_enc = (unsigned short*)d_ws;                 // 128 KB
  unsigned short* wt_dec = wt_enc + NZ * KWT;                     // +128 KB
  unsigned short* xw_enc = wt_dec + NZ * KWT;                     // +32 KB
  unsigned short* xw_dec = xw_enc + NZ * XK;                      // +32 KB

  hipLaunchKernelGGL(prep_weights, dim3(2 * NZ), dim3(64), 0, stream,
                     We, be, Wih_e, Whh_e, b_e, Wd, bd, Wih_d, Whh_d, b_d,
                     Wo, bo, wt_enc, wt_dec, xw_enc, xw_dec);
  hipLaunchKernelGGL(lstm_fused, dim3(BATCH / 64), dim3(512), 0, stream,
                     obs, wt_enc, wt_dec, xw_enc, xw_dec, Wo, bo, out);
}

// Round 13
// 502.156 us; speedup vs baseline: 1.1033x; 1.1033x over previous
//
#include <hip/hip_runtime.h>

// Round 13 = r11 base (stagger/setprio reverted) + three issue-count cuts:
//  1) decoder MMX drops the K=32 x-block (A2 was constant [0,0,1,0,0]):
//     acc initialized from pre-scaled f32 bias regs (bbD) instead -> 32 MFMA
//     not 40 in all decoder phases; decoder A2 staging deleted.
//  2) Wo hoisted to 16 regs/lane (wo0..wo3); POSC does 1 LDS read + FMAs.
//  3) GATE/POS/STAGE placed BEFORE MM in every phase (serial trans chain
//     early, throughput MFMA tail), uniform order, no branch.
// Structure: 512 thr (8 waves, 2/SIMD, 256-reg, spill-free), 64 rows/block
// as two 32-row chunks interleaved, 1 barrier/phase, 4-bit XOR swizzle,
// weights pre-scaled by -log2e / -2log2e, encoder obs+bias via K=32 MFMA
// fold (exact hi/lo), decoder pos-path folded into Whh_d, c in f32 regs.

#define OBS_LEN 8
#define PRED_LEN 12
#define BATCH 131072
#define HID 128
#define NZ 512
#define KWT 128
#define XK 32
#define A2S 40          // A2 row stride (u16): 80B -> 2-way banks (free)

typedef float f32x4 __attribute__((ext_vector_type(4)));
typedef float f32x2 __attribute__((ext_vector_type(2)));
typedef unsigned short u16x8 __attribute__((ext_vector_type(8)));
typedef __bf16 bf16x8 __attribute__((ext_vector_type(8)));

#define K2F 1.4426950408889634f   // log2(e)

static __device__ __forceinline__ unsigned short cvt1(float f) {
  __bf16 b = (__bf16)f;
  return __builtin_bit_cast(unsigned short, b);
}
static __device__ __forceinline__ float bf2f(unsigned short h) {
  return __uint_as_float(((unsigned int)h) << 16);
}

// ---------------- prep ----------------
// Permuted col c: cg=c>>6, gate=(c>>4)&3, cl=c&15; unit=cg*16+cl; n=gate*128+unit.
// Scale s = -2*log2e for gate g (index 2), else -log2e.
// wt[c][k] = bf16(s * (Whh[k][n] (+ dec pos-fold)))
// enc: xw[c][0..4] = bf16(s*{wx,wy,bias,wx,wy}); dec: auxf[c] = f32 s*bias.
__global__ void prep_weights(const float* __restrict__ We,   const float* __restrict__ be,
                             const float* __restrict__ Wih_e,const float* __restrict__ Whh_e,
                             const float* __restrict__ b_e,
                             const float* __restrict__ Wd,   const float* __restrict__ bd,
                             const float* __restrict__ Wih_d,const float* __restrict__ Whh_d,
                             const float* __restrict__ b_d,
                             const float* __restrict__ Wo,   const float* __restrict__ bo,
                             unsigned short* __restrict__ wt_enc,
                             unsigned short* __restrict__ wt_dec,
                             unsigned short* __restrict__ xw_enc,
                             float* __restrict__ auxf_dec) {
  const int c = blockIdx.x & (NZ - 1);
  const bool dec = blockIdx.x >= NZ;
  const int cg = c >> 6, gate = (c >> 4) & 3, cl = c & 15;
  const int unit = cg * 16 + cl;
  const int n = gate * HID + unit;
  const float s = (gate == 2) ? (-2.f * K2F) : (-K2F);

  const float* Whh = dec ? Whh_d : Whh_e;
  const float* Wih = dec ? Wih_d : Wih_e;
  const float* Wem = dec ? Wd : We;
  const float* bem = dec ? bd : be;
  const float* bl  = dec ? b_d : b_e;
  unsigned short* wt = dec ? wt_dec : wt_enc;

  float wx = 0.f, wy = 0.f;
  for (int e = 0; e < HID; ++e) {
    wx += Wem[e] * Wih[e * NZ + n];
    wy += Wem[HID + e] * Wih[e * NZ + n];
  }
  for (int k = threadIdx.x; k < KWT; k += 64) {
    float v = Whh[k * NZ + n];
    if (dec) v += Wo[k * 2] * wx + Wo[k * 2 + 1] * wy;
    wt[c * KWT + k] = cvt1(s * v);
  }
  if (threadIdx.x == 0) {
    float bb = bl[n];
    for (int e = 0; e < HID; ++e) bb += bem[e] * Wih[e * NZ + n];
    if (dec) {
      bb += bo[0] * wx + bo[1] * wy;
      auxf_dec[c] = s * bb;
    } else {
      unsigned short* xr = xw_enc + c * XK;
      for (int k = 5; k < XK; ++k) xr[k] = 0;
      xr[0] = cvt1(s * wx); xr[1] = cvt1(s * wy); xr[2] = cvt1(s * bb);
      xr[3] = xr[0]; xr[4] = xr[1];
    }
  }
}

// ---------------- main fused kernel ----------------
// MFMA 16x16x32 bf16 (HW-verified r1-r12):
//  A/B frag: row/col = lane&15, k = 32kc + (lane>>4)*8 + j
//  C/D: col = lane&15, row = (lane>>4)*4 + reg
// hL swizzle (4-bit, bijective): elem(r,k) = r*128 + (((k>>3)^(r&15))<<3)+(k&7)

#define MFMA(A, B, C)                                                          \
  __builtin_amdgcn_mfma_f32_16x16x32_bf16(                                     \
      __builtin_bit_cast(bf16x8, (A)), __builtin_bit_cast(bf16x8, (B)), (C),   \
      0, 0, 0)

#define EXP4(D, S)                                                             \
  { f32x4 _s = (S);                                                            \
    D[0] = __builtin_amdgcn_exp2f(_s[0]); D[1] = __builtin_amdgcn_exp2f(_s[1]);\
    D[2] = __builtin_amdgcn_exp2f(_s[2]); D[3] = __builtin_amdgcn_exp2f(_s[3]); }
#define RCP4(D, S)                                                             \
  { f32x4 _r = (S);                                                            \
    D[0] = __builtin_amdgcn_rcpf(_r[0]); D[1] = __builtin_amdgcn_rcpf(_r[1]);  \
    D[2] = __builtin_amdgcn_rcpf(_r[2]); D[3] = __builtin_amdgcn_rcpf(_r[3]); }

#define LOADW_BF(WT)                                                           \
  { _Pragma("unroll")                                                          \
    for (int kc = 0; kc < 4; ++kc) {                                           \
      _Pragma("unroll")                                                        \
      for (int g = 0; g < 4; ++g)                                              \
        bfr[kc][g] =                                                           \
            *(const u16x8*)&(WT)[(cg * 64 + g * 16 + l15) * KWT + kc * 32 +    \
                                 l4 * 8];                                      \
    } }

// K=128 hidden matmul for chunk X (acc must be pre-initialized)
#define MMH(ACC, X)                                                            \
  { _Pragma("unroll")                                                          \
    for (int kc = 0; kc < 4; ++kc) {                                           \
      const int mm_g = (((kc * 4 + l4) ^ l15) << 3);                           \
      u16x8 mm_a0 = *(const u16x8*)&hL[(X)*4096 + l15 * 128 + mm_g];           \
      u16x8 mm_a1 = *(const u16x8*)&hL[(X)*4096 + (16 + l15) * 128 + mm_g];    \
      _Pragma("unroll")                                                        \
      for (int g = 0; g < 4; ++g) {                                            \
        ACC[0][g] = MFMA(mm_a0, bfr[kc][g], ACC[0][g]);                        \
        ACC[1][g] = MFMA(mm_a1, bfr[kc][g], ACC[1][g]);                        \
      } } }

// encoder matmul: K=32 x-block (obs fold + bias, zero-C) then K=128 hidden
#define MMXE(ACC, X)                                                           \
  { u16x8 mm_a2a = *(const u16x8*)&A2[(X)*32 * A2S + l15 * A2S + l4 * 8];      \
    u16x8 mm_a2b =                                                             \
        *(const u16x8*)&A2[(X)*32 * A2S + (16 + l15) * A2S + l4 * 8];          \
    _Pragma("unroll")                                                          \
    for (int g = 0; g < 4; ++g) {                                              \
      ACC[0][g] = MFMA(mm_a2a, xfr[g], ZROV);                                  \
      ACC[1][g] = MFMA(mm_a2b, xfr[g], ZROV);                                  \
    }                                                                          \
    MMH(ACC, X) }

// decoder acc init: pre-scaled f32 bias (incl pos-fold) broadcast
#define INITD(ACC)                                                             \
  { _Pragma("unroll")                                                          \
    for (int m = 0; m < 2; ++m) {                                              \
      _Pragma("unroll")                                                        \
      for (int g = 0; g < 4; ++g)                                              \
        ACC[m][g] = (f32x4){bbD[g], bbD[g], bbD[g], bbD[g]};                   \
    } }

// gate for chunk X: acc already = scaled z (incl input fold + bias)
#define GATEC(ACC, CRR, X)                                                     \
  { _Pragma("unroll")                                                          \
    for (int m = 0; m < 2; ++m) {                                              \
      f32x4 g_eB, g_eA, g_eG, g_eO;                                            \
      EXP4(g_eB, ACC[m][0]) EXP4(g_eA, ACC[m][1])                              \
      EXP4(g_eG, ACC[m][2]) EXP4(g_eO, ACC[m][3])                              \
      f32x4 g_a1 = 1.f + g_eA, g_b1 = 1.f + g_eB, g_g1 = 1.f + g_eG;           \
      f32x4 g_bg = g_b1 * g_g1;                                                \
      f32x4 g_rd; RCP4(g_rd, g_a1 * g_bg)                                      \
      f32x4 g_cv = (CRR[m] * g_bg + (1.f - g_eG) * g_a1) * g_rd;               \
      CRR[m] = g_cv;                                                           \
      f32x4 g_eC; EXP4(g_eC, g_cv * (-2.f * K2F))                              \
      f32x4 g_rh; RCP4(g_rh, (1.f + g_eO) * (1.f + g_eC))                      \
      f32x4 g_hv = (1.f - g_eC) * g_rh;                                        \
      const int g_R0 = 16 * m + l4 * 4;                                        \
      _Pragma("unroll")                                                        \
      for (int r = 0; r < 4; ++r)                                              \
        hL[(X)*4096 + (g_R0 + r) * 128 +                                       \
           ((uh ^ ((g_R0 + r) & 15)) << 3) + ul] = cvt1(g_hv[r]);              \
    } }

// pos = h @ Wo + bo, fire-and-forget; Wo slice in regs wo0..wo3.
#define POSC(S, X)                                                             \
  { const int pp_r = tid >> 4;                                                 \
    u16x8 pp_h = *(const u16x8*)&hL[(X)*4096 + pp_r * 128 +                    \
                                    ((pq ^ (pp_r & 15)) << 3)];                \
    f32x2 pp_s = (f32x2){0.f, 0.f};                                            \
    pp_s += bf2f(pp_h[0]) * (f32x2){wo0[0], wo0[1]};                           \
    pp_s += bf2f(pp_h[1]) * (f32x2){wo0[2], wo0[3]};                           \
    pp_s += bf2f(pp_h[2]) * (f32x2){wo1[0], wo1[1]};                           \
    pp_s += bf2f(pp_h[3]) * (f32x2){wo1[2], wo1[3]};                           \
    pp_s += bf2f(pp_h[4]) * (f32x2){wo2[0], wo2[1]};                           \
    pp_s += bf2f(pp_h[5]) * (f32x2){wo2[2], wo2[3]};                           \
    pp_s += bf2f(pp_h[6]) * (f32x2){wo3[0], wo3[1]};                           \
    pp_s += bf2f(pp_h[7]) * (f32x2){wo3[2], wo3[3]};                           \
    pp_s[0] += __shfl_xor(pp_s[0], 1); pp_s[1] += __shfl_xor(pp_s[1], 1);      \
    pp_s[0] += __shfl_xor(pp_s[0], 2); pp_s[1] += __shfl_xor(pp_s[1], 2);      \
    pp_s[0] += __shfl_xor(pp_s[0], 4); pp_s[1] += __shfl_xor(pp_s[1], 4);      \
    pp_s[0] += __shfl_xor(pp_s[0], 8); pp_s[1] += __shfl_xor(pp_s[1], 8);      \
    if (pq == 0) {                                                             \
      float2 pp_o; pp_o.x = pp_s[0] + bo0; pp_o.y = pp_s[1] + bo1;             \
      ((float2*)out)[(size_t)(S)*BATCH + row0 + (X)*32 + pp_r] = pp_o;         \
    } }

// stage encoder A2 for chunk X, step T (exact hi/lo split)
#define STAGE_OBS_A2(T, X)                                                     \
  if (tid < 32) {                                                              \
    float2 so_p =                                                              \
        ((const float2*)obs)[(size_t)(T)*BATCH + row0 + (X)*32 + tid];         \
    unsigned short so_x = cvt1(so_p.x), so_y = cvt1(so_p.y);                   \
    unsigned short* so_r = &A2[(X)*32 * A2S + tid * A2S];                      \
    so_r[0] = so_x; so_r[1] = so_y; so_r[2] = 0x3F80u;                         \
    so_r[3] = cvt1(so_p.x - bf2f(so_x));                                       \
    so_r[4] = cvt1(so_p.y - bf2f(so_y));                                       \
  }

__global__ __launch_bounds__(512, 2) void lstm_fused(
    const float* __restrict__ obs,
    const unsigned short* __restrict__ wt_enc,
    const unsigned short* __restrict__ wt_dec,
    const unsigned short* __restrict__ xw_enc,
    const float* __restrict__ auxf_dec,
    const float* __restrict__ Wo, const float* __restrict__ bo,
    float* __restrict__ out) {
  __shared__ unsigned short hL[2 * 32 * 128];   // 16 KB, 4-bit XOR-swizzled
  __shared__ unsigned short A2[2 * 32 * A2S];   // 5 KB

  const int tid = threadIdx.x;
  const int lane = tid & 63;
  const int cg = tid >> 6;          // wave 0..7 -> cols [64cg, 64cg+64)
  const int l15 = lane & 15;
  const int l4 = lane >> 4;
  const int pq = tid & 15;          // POSC unit-slice id
  const int row0 = blockIdx.x * 64;
  const int u = cg * 16 + l15, uh = u >> 3, ul = u & 7;
  const float bo0 = bo[0], bo1 = bo[1];
  const f32x4 ZROV = {0.f, 0.f, 0.f, 0.f};

  // ---- P0a: zero hL + A2; Wo slice + weights into regs ----
  {
    u16x8 z8 = (u16x8){0, 0, 0, 0, 0, 0, 0, 0};
    *(u16x8*)&hL[tid * 8] = z8;                      // 512*8 = 4096
    *(u16x8*)&hL[4096 + tid * 8] = z8;
    unsigned short* az = &A2[tid * 5];               // 512*5 = 2560 = 2*32*40
    az[0] = 0; az[1] = 0; az[2] = 0; az[3] = 0; az[4] = 0;
  }
  const float* wop = Wo + pq * 16;
  const f32x4 wo0 = *(const f32x4*)wop;
  const f32x4 wo1 = *(const f32x4*)(wop + 4);
  const f32x4 wo2 = *(const f32x4*)(wop + 8);
  const f32x4 wo3 = *(const f32x4*)(wop + 12);

  u16x8 bfr[4][4], xfr[4];          // persistent weights: 80 regs
  LOADW_BF(wt_enc);
#pragma unroll
  for (int g = 0; g < 4; ++g)
    xfr[g] = *(const u16x8*)&xw_enc[(cg * 64 + g * 16 + l15) * XK + l4 * 8];

  f32x4 accA[2][4], accB[2][4];
  f32x4 crrA[2], crrB[2];
  crrA[0] = crrA[1] = ZROV;
  crrB[0] = crrB[1] = ZROV;
  __syncthreads();

  // ---- P0b: stage A2_A(0). (A2_B(0) is staged in alpha(0).) ----
  STAGE_OBS_A2(0, 0)
  __syncthreads();

  // ---- encoder t = 0..7 (GATE/STAGE first, MM last) ----
#pragma unroll 1
  for (int t = 0; t < OBS_LEN; ++t) {
    // alpha(t)
    if (t > 0) { GATEC(accB, crrB, 1) }
    STAGE_OBS_A2(t, 1)
    MMXE(accA, 0)
    __syncthreads();
    // beta(t)
    GATEC(accA, crrA, 0)
    if (t + 1 < OBS_LEN) { STAGE_OBS_A2(t + 1, 0) }
    MMXE(accB, 1)
    __syncthreads();
  }

  // ---- transition: decoder weights + f32 bias; reset c for chunk A ----
  LOADW_BF(wt_dec);
  float bbD[4];
#pragma unroll
  for (int g = 0; g < 4; ++g) bbD[g] = auxf_dec[cg * 64 + g * 16 + l15];
  crrA[0] = crrA[1] = ZROV;

  // alpha_d(1): GATE_B(7,enc) + POSC_A(0) ; dec MM_A(1)
  GATEC(accB, crrB, 1)
  POSC(0, 0)
  INITD(accA)
  MMH(accA, 0)
  __syncthreads();
  crrB[0] = crrB[1] = ZROV;

  // beta_d(1): GATE_A^dec(1) + POSC_B(0) ; dec MM_B(1)
  GATEC(accA, crrA, 0)
  POSC(0, 1)
  INITD(accB)
  MMH(accB, 1)
  __syncthreads();

  // ---- decoder d = 2..11 ----
#pragma unroll 1
  for (int d = 2; d < PRED_LEN; ++d) {
    GATEC(accB, crrB, 1)
    POSC(d - 1, 0)
    INITD(accA)
    MMH(accA, 0)
    __syncthreads();
    GATEC(accA, crrA, 0)
    POSC(d - 1, 1)
    INITD(accB)
    MMH(accB, 1)
    __syncthreads();
  }

  // ---- epilogue ----
  GATEC(accB, crrB, 1)
  POSC(PRED_LEN - 1, 0)
  __syncthreads();
  POSC(PRED_LEN - 1, 1)
}

extern "C" void kernel_launch(void* const* d_in, const int* in_sizes, int n_in,
                              void* d_out, int out_size, void* d_ws, size_t ws_size,
                              hipStream_t stream) {
  const float* obs   = (const float*)d_in[0];
  const float* We    = (const float*)d_in[1];
  const float* be    = (const float*)d_in[2];
  const float* Wih_e = (const float*)d_in[3];
  const float* Whh_e = (const float*)d_in[4];
  const float* b_e   = (const float*)d_in[5];
  const float* Wd    = (const float*)d_in[6];
  const float* bd    = (const float*)d_in[7];
  const float* Wih_d = (const float*)d_in[8];
  const float* Whh_d = (const float*)d_in[9];
  const float* b_d   = (const float*)d_in[10];
  const float* Wo    = (const float*)d_in[11];
  const float* bo    = (const float*)d_in[12];
  float* out = (float*)d_out;

  unsigned short* wt_enc = (unsigned short*)d_ws;                 // 128 KB
  unsigned short* wt_dec = wt_enc + NZ * KWT;                     // +128 KB
  unsigned short* xw_enc = wt_dec + NZ * KWT;                     // +32 KB
  float* auxf_dec = (float*)(xw_enc + NZ * XK);                   // +2 KB

  hipLaunchKernelGGL(prep_weights, dim3(2 * NZ), dim3(64), 0, stream,
                     We, be, Wih_e, Whh_e, b_e, Wd, bd, Wih_d, Whh_d, b_d,
                     Wo, bo, wt_enc, wt_dec, xw_enc, auxf_dec);
  hipLaunchKernelGGL(lstm_fused, dim3(BATCH / 64), dim3(512), 0, stream,
                     obs, wt_enc, wt_dec, xw_enc, auxf_dec, Wo, bo, out);
}

// Round 14
// 501.011 us; speedup vs baseline: 1.1058x; 1.0023x over previous
//
#include <hip/hip_runtime.h>

// Round 14 = r13 + merged phases (1 barrier/step, was 2) via h double-buffer.
// Per step: {STAGE_A2(t+1) | MM_A | MM_B | [POS] | GATE_A | GATE_B} barrier.
// MM reads h[p], GATE writes h[p^1] -> no intra-phase cross-wave hazard;
// single barrier separates GATE(t) writes from MM(t+1) reads. A2 is also
// double-buffered. Decoder acc init via MFMA C-operand = bias regs (bbV),
// deleting 32 v_movs per MM. Everything else from r13: 512 thr (8 waves,
// 2/SIMD, 256-reg), 4-bit XOR swizzle, prescaled weights (-log2e/-2log2e),
// encoder obs+bias as K=32 MFMA fold (exact hi/lo), decoder pos-path folded
// into Whh_d, Wo in regs, c in f32 regs.

#define OBS_LEN 8
#define PRED_LEN 12
#define BATCH 131072
#define HID 128
#define NZ 512
#define KWT 128
#define XK 32
#define A2S 40          // A2 row stride (u16): 80B
#define A2Q (2 * 32 * A2S)   // one A2 pbuf (both chunks), u16

typedef float f32x4 __attribute__((ext_vector_type(4)));
typedef float f32x2 __attribute__((ext_vector_type(2)));
typedef unsigned short u16x8 __attribute__((ext_vector_type(8)));
typedef __bf16 bf16x8 __attribute__((ext_vector_type(8)));

#define K2F 1.4426950408889634f   // log2(e)

static __device__ __forceinline__ unsigned short cvt1(float f) {
  __bf16 b = (__bf16)f;
  return __builtin_bit_cast(unsigned short, b);
}
static __device__ __forceinline__ float bf2f(unsigned short h) {
  return __uint_as_float(((unsigned int)h) << 16);
}

// ---------------- prep (r13-verified, unchanged) ----------------
__global__ void prep_weights(const float* __restrict__ We,   const float* __restrict__ be,
                             const float* __restrict__ Wih_e,const float* __restrict__ Whh_e,
                             const float* __restrict__ b_e,
                             const float* __restrict__ Wd,   const float* __restrict__ bd,
                             const float* __restrict__ Wih_d,const float* __restrict__ Whh_d,
                             const float* __restrict__ b_d,
                             const float* __restrict__ Wo,   const float* __restrict__ bo,
                             unsigned short* __restrict__ wt_enc,
                             unsigned short* __restrict__ wt_dec,
                             unsigned short* __restrict__ xw_enc,
                             float* __restrict__ auxf_dec) {
  const int c = blockIdx.x & (NZ - 1);
  const bool dec = blockIdx.x >= NZ;
  const int cg = c >> 6, gate = (c >> 4) & 3, cl = c & 15;
  const int unit = cg * 16 + cl;
  const int n = gate * HID + unit;
  const float s = (gate == 2) ? (-2.f * K2F) : (-K2F);

  const float* Whh = dec ? Whh_d : Whh_e;
  const float* Wih = dec ? Wih_d : Wih_e;
  const float* Wem = dec ? Wd : We;
  const float* bem = dec ? bd : be;
  const float* bl  = dec ? b_d : b_e;
  unsigned short* wt = dec ? wt_dec : wt_enc;

  float wx = 0.f, wy = 0.f;
  for (int e = 0; e < HID; ++e) {
    wx += Wem[e] * Wih[e * NZ + n];
    wy += Wem[HID + e] * Wih[e * NZ + n];
  }
  for (int k = threadIdx.x; k < KWT; k += 64) {
    float v = Whh[k * NZ + n];
    if (dec) v += Wo[k * 2] * wx + Wo[k * 2 + 1] * wy;
    wt[c * KWT + k] = cvt1(s * v);
  }
  if (threadIdx.x == 0) {
    float bb = bl[n];
    for (int e = 0; e < HID; ++e) bb += bem[e] * Wih[e * NZ + n];
    if (dec) {
      bb += bo[0] * wx + bo[1] * wy;
      auxf_dec[c] = s * bb;
    } else {
      unsigned short* xr = xw_enc + c * XK;
      for (int k = 5; k < XK; ++k) xr[k] = 0;
      xr[0] = cvt1(s * wx); xr[1] = cvt1(s * wy); xr[2] = cvt1(s * bb);
      xr[3] = xr[0]; xr[4] = xr[1];
    }
  }
}

// ---------------- main fused kernel ----------------
// MFMA 16x16x32 bf16 (HW-verified r1-r13):
//  A/B frag: row/col = lane&15, k = 32kc + (lane>>4)*8 + j
//  C/D: col = lane&15, row = (lane>>4)*4 + reg
// hL: [chunk][pbuf][32][128] u16, 4-bit XOR swizzle
//  elem(X,P,r,k) = X*8192 + P*4096 + r*128 + (((k>>3)^(r&15))<<3) + (k&7)

#define MFMA(A, B, C)                                                          \
  __builtin_amdgcn_mfma_f32_16x16x32_bf16(                                     \
      __builtin_bit_cast(bf16x8, (A)), __builtin_bit_cast(bf16x8, (B)), (C),   \
      0, 0, 0)

#define EXP4(D, S)                                                             \
  { f32x4 _s = (S);                                                            \
    D[0] = __builtin_amdgcn_exp2f(_s[0]); D[1] = __builtin_amdgcn_exp2f(_s[1]);\
    D[2] = __builtin_amdgcn_exp2f(_s[2]); D[3] = __builtin_amdgcn_exp2f(_s[3]); }
#define RCP4(D, S)                                                             \
  { f32x4 _r = (S);                                                            \
    D[0] = __builtin_amdgcn_rcpf(_r[0]); D[1] = __builtin_amdgcn_rcpf(_r[1]);  \
    D[2] = __builtin_amdgcn_rcpf(_r[2]); D[3] = __builtin_amdgcn_rcpf(_r[3]); }

#define LOADW_BF(WT)                                                           \
  { _Pragma("unroll")                                                          \
    for (int kc = 0; kc < 4; ++kc) {                                           \
      _Pragma("unroll")                                                        \
      for (int g = 0; g < 4; ++g)                                              \
        bfr[kc][g] =                                                           \
            *(const u16x8*)&(WT)[(cg * 64 + g * 16 + l15) * KWT + kc * 32 +    \
                                 l4 * 8];                                      \
    } }

// K=128 hidden matmul, accumulate into pre-set ACC, h from buf P
#define MMH(ACC, X, P)                                                         \
  { _Pragma("unroll")                                                          \
    for (int kc = 0; kc < 4; ++kc) {                                           \
      const int mm_g = (((kc * 4 + l4) ^ l15) << 3);                           \
      const int mb = (X)*8192 + (P)*4096;                                      \
      u16x8 mm_a0 = *(const u16x8*)&hL[mb + l15 * 128 + mm_g];                 \
      u16x8 mm_a1 = *(const u16x8*)&hL[mb + (16 + l15) * 128 + mm_g];          \
      _Pragma("unroll")                                                        \
      for (int g = 0; g < 4; ++g) {                                            \
        ACC[0][g] = MFMA(mm_a0, bfr[kc][g], ACC[0][g]);                        \
        ACC[1][g] = MFMA(mm_a1, bfr[kc][g], ACC[1][g]);                        \
      } } }

// encoder MM: K=32 x-block (obs fold + bias, zero-C) then K=128 hidden
#define MMXE(ACC, X, P, Q)                                                     \
  { u16x8 mm_a2a =                                                             \
        *(const u16x8*)&A2[(Q)*A2Q + ((X)*32 + l15) * A2S + l4 * 8];           \
    u16x8 mm_a2b =                                                             \
        *(const u16x8*)&A2[(Q)*A2Q + ((X)*32 + 16 + l15) * A2S + l4 * 8];      \
    _Pragma("unroll")                                                          \
    for (int g = 0; g < 4; ++g) {                                              \
      ACC[0][g] = MFMA(mm_a2a, xfr[g], ZROV);                                  \
      ACC[1][g] = MFMA(mm_a2b, xfr[g], ZROV);                                  \
    }                                                                          \
    MMH(ACC, X, P) }

// decoder MM: kc=0 uses bias regs as MFMA C-operand (no acc init movs)
#define MMHD(ACC, X, P)                                                        \
  { { const int mm_g = ((l4 ^ l15) << 3);                                      \
      const int mb = (X)*8192 + (P)*4096;                                      \
      u16x8 mm_a0 = *(const u16x8*)&hL[mb + l15 * 128 + mm_g];                 \
      u16x8 mm_a1 = *(const u16x8*)&hL[mb + (16 + l15) * 128 + mm_g];          \
      _Pragma("unroll")                                                        \
      for (int g = 0; g < 4; ++g) {                                            \
        ACC[0][g] = MFMA(mm_a0, bfr[0][g], bbV[g]);                            \
        ACC[1][g] = MFMA(mm_a1, bfr[0][g], bbV[g]);                            \
      } }                                                                      \
    _Pragma("unroll")                                                          \
    for (int kc = 1; kc < 4; ++kc) {                                           \
      const int mm_g = (((kc * 4 + l4) ^ l15) << 3);                           \
      const int mb = (X)*8192 + (P)*4096;                                      \
      u16x8 mm_a0 = *(const u16x8*)&hL[mb + l15 * 128 + mm_g];                 \
      u16x8 mm_a1 = *(const u16x8*)&hL[mb + (16 + l15) * 128 + mm_g];          \
      _Pragma("unroll")                                                        \
      for (int g = 0; g < 4; ++g) {                                            \
        ACC[0][g] = MFMA(mm_a0, bfr[kc][g], ACC[0][g]);                        \
        ACC[1][g] = MFMA(mm_a1, bfr[kc][g], ACC[1][g]);                        \
      } } }

// gate for chunk X: acc = scaled z; writes h into buf P
#define GATEC(ACC, CRR, X, P)                                                  \
  { _Pragma("unroll")                                                          \
    for (int m = 0; m < 2; ++m) {                                              \
      f32x4 g_eB, g_eA, g_eG, g_eO;                                            \
      EXP4(g_eB, ACC[m][0]) EXP4(g_eA, ACC[m][1])                              \
      EXP4(g_eG, ACC[m][2]) EXP4(g_eO, ACC[m][3])                              \
      f32x4 g_a1 = 1.f + g_eA, g_b1 = 1.f + g_eB, g_g1 = 1.f + g_eG;           \
      f32x4 g_bg = g_b1 * g_g1;                                                \
      f32x4 g_rd; RCP4(g_rd, g_a1 * g_bg)                                      \
      f32x4 g_cv = (CRR[m] * g_bg + (1.f - g_eG) * g_a1) * g_rd;               \
      CRR[m] = g_cv;                                                           \
      f32x4 g_eC; EXP4(g_eC, g_cv * (-2.f * K2F))                              \
      f32x4 g_rh; RCP4(g_rh, (1.f + g_eO) * (1.f + g_eC))                      \
      f32x4 g_hv = (1.f - g_eC) * g_rh;                                        \
      const int g_R0 = 16 * m + l4 * 4;                                        \
      _Pragma("unroll")                                                        \
      for (int r = 0; r < 4; ++r)                                              \
        hL[(X)*8192 + (P)*4096 + (g_R0 + r) * 128 +                            \
           ((uh ^ ((g_R0 + r) & 15)) << 3) + ul] = cvt1(g_hv[r]);              \
    } }

// pos = h @ Wo + bo, fire-and-forget; Wo slice in regs; h from buf P
#define POSC(S, X, P)                                                          \
  { const int pp_r = tid >> 4;                                                 \
    u16x8 pp_h = *(const u16x8*)&hL[(X)*8192 + (P)*4096 + pp_r * 128 +         \
                                    ((pq ^ (pp_r & 15)) << 3)];                \
    f32x2 pp_s = (f32x2){0.f, 0.f};                                            \
    pp_s += bf2f(pp_h[0]) * (f32x2){wo0[0], wo0[1]};                           \
    pp_s += bf2f(pp_h[1]) * (f32x2){wo0[2], wo0[3]};                           \
    pp_s += bf2f(pp_h[2]) * (f32x2){wo1[0], wo1[1]};                           \
    pp_s += bf2f(pp_h[3]) * (f32x2){wo1[2], wo1[3]};                           \
    pp_s += bf2f(pp_h[4]) * (f32x2){wo2[0], wo2[1]};                           \
    pp_s += bf2f(pp_h[5]) * (f32x2){wo2[2], wo2[3]};                           \
    pp_s += bf2f(pp_h[6]) * (f32x2){wo3[0], wo3[1]};                           \
    pp_s += bf2f(pp_h[7]) * (f32x2){wo3[2], wo3[3]};                           \
    pp_s[0] += __shfl_xor(pp_s[0], 1); pp_s[1] += __shfl_xor(pp_s[1], 1);      \
    pp_s[0] += __shfl_xor(pp_s[0], 2); pp_s[1] += __shfl_xor(pp_s[1], 2);      \
    pp_s[0] += __shfl_xor(pp_s[0], 4); pp_s[1] += __shfl_xor(pp_s[1], 4);      \
    pp_s[0] += __shfl_xor(pp_s[0], 8); pp_s[1] += __shfl_xor(pp_s[1], 8);      \
    if (pq == 0) {                                                             \
      float2 pp_o; pp_o.x = pp_s[0] + bo0; pp_o.y = pp_s[1] + bo1;             \
      ((float2*)out)[(size_t)(S)*BATCH + row0 + (X)*32 + pp_r] = pp_o;         \
    } }

// stage A2 rows for BOTH chunks (64 rows), step T, into pbuf Q
#define STAGE_A2(T, Q)                                                         \
  if (tid < 64) {                                                              \
    float2 so_p = ((const float2*)obs)[(size_t)(T)*BATCH + row0 + tid];        \
    unsigned short so_x = cvt1(so_p.x), so_y = cvt1(so_p.y);                   \
    unsigned short* so_r = &A2[(Q)*A2Q + tid * A2S];                           \
    so_r[0] = so_x; so_r[1] = so_y; so_r[2] = 0x3F80u;                         \
    so_r[3] = cvt1(so_p.x - bf2f(so_x));                                       \
    so_r[4] = cvt1(so_p.y - bf2f(so_y));                                       \
  }

__global__ __launch_bounds__(512, 2) void lstm_fused(
    const float* __restrict__ obs,
    const unsigned short* __restrict__ wt_enc,
    const unsigned short* __restrict__ wt_dec,
    const unsigned short* __restrict__ xw_enc,
    const float* __restrict__ auxf_dec,
    const float* __restrict__ Wo, const float* __restrict__ bo,
    float* __restrict__ out) {
  __shared__ unsigned short hL[2 * 2 * 32 * 128];   // 32 KB: [chunk][pbuf]
  __shared__ unsigned short A2[2 * A2Q];            // 10 KB: [pbuf][chunk rows]

  const int tid = threadIdx.x;
  const int lane = tid & 63;
  const int cg = tid >> 6;          // wave 0..7 -> cols [64cg, 64cg+64)
  const int l15 = lane & 15;
  const int l4 = lane >> 4;
  const int pq = tid & 15;          // POSC unit-slice id
  const int row0 = blockIdx.x * 64;
  const int u = cg * 16 + l15, uh = u >> 3, ul = u & 7;
  const float bo0 = bo[0], bo1 = bo[1];
  const f32x4 ZROV = {0.f, 0.f, 0.f, 0.f};

  // ---- P0: zero h pbuf0 (both chunks) + all A2; load weights/Wo ----
  {
    u16x8 z8 = (u16x8){0, 0, 0, 0, 0, 0, 0, 0};
    *(u16x8*)&hL[tid * 8] = z8;                 // chunk0 p0: 0..4095
    *(u16x8*)&hL[8192 + tid * 8] = z8;          // chunk1 p0: 8192..12287
    unsigned short* az = &A2[tid * 10];         // 512*10 = 5120 = 2*A2Q
    az[0] = 0; az[1] = 0; az[2] = 0; az[3] = 0; az[4] = 0;
    az[5] = 0; az[6] = 0; az[7] = 0; az[8] = 0; az[9] = 0;
  }
  const float* wop = Wo + pq * 16;
  const f32x4 wo0 = *(const f32x4*)wop;
  const f32x4 wo1 = *(const f32x4*)(wop + 4);
  const f32x4 wo2 = *(const f32x4*)(wop + 8);
  const f32x4 wo3 = *(const f32x4*)(wop + 12);

  u16x8 bfr[4][4], xfr[4];          // persistent weights: 80 regs
  LOADW_BF(wt_enc);
#pragma unroll
  for (int g = 0; g < 4; ++g)
    xfr[g] = *(const u16x8*)&xw_enc[(cg * 64 + g * 16 + l15) * XK + l4 * 8];

  f32x4 accA[2][4], accB[2][4];
  f32x4 crrA[2], crrB[2];
  crrA[0] = crrA[1] = ZROV;
  crrB[0] = crrB[1] = ZROV;
  __syncthreads();

  // ---- stage A2(0) into q=0 ----
  STAGE_A2(0, 0)
  __syncthreads();

  // ---- encoder t = 0..7: ONE phase/step ----
  // step t: reads h[p=t&1], A2[q=t&1]; writes h[p^1]; stages A2(t+1)->q^1
#pragma unroll 1
  for (int t = 0; t < OBS_LEN; ++t) {
    const int p = t & 1;
    if (t + 1 < OBS_LEN) { STAGE_A2(t + 1, p ^ 1) }
    MMXE(accA, 0, p, p)
    MMXE(accB, 1, p, p)
    GATEC(accA, crrA, 0, p ^ 1)
    GATEC(accB, crrB, 1, p ^ 1)
    __syncthreads();
  }
  // h_enc now in pbuf (7&1)^1 = 0

  // ---- transition: decoder weights + bias regs; reset c ----
  LOADW_BF(wt_dec);
  f32x4 bbV[4];
#pragma unroll
  for (int g = 0; g < 4; ++g) {
    float b_ = auxf_dec[cg * 64 + g * 16 + l15];
    bbV[g] = (f32x4){b_, b_, b_, b_};
  }
  crrA[0] = crrA[1] = ZROV;
  crrB[0] = crrB[1] = ZROV;

  // ---- decoder d = 1..11: ONE phase/step ----
  // step d: reads h[p=(d-1)&1] (h(d-1)); POSC(d-1) reads same buf;
  // writes h(d) into p^1.
#pragma unroll 1
  for (int d = 1; d < PRED_LEN; ++d) {
    const int p = (d - 1) & 1;
    MMHD(accA, 0, p)
    MMHD(accB, 1, p)
    POSC(d - 1, 0, p)
    POSC(d - 1, 1, p)
    GATEC(accA, crrA, 0, p ^ 1)
    GATEC(accB, crrB, 1, p ^ 1)
    __syncthreads();
  }

  // ---- epilogue: h(11) is in pbuf ((11-1)&1)^1 = 1 ----
  POSC(PRED_LEN - 1, 0, 1)
  POSC(PRED_LEN - 1, 1, 1)
}

extern "C" void kernel_launch(void* const* d_in, const int* in_sizes, int n_in,
                              void* d_out, int out_size, void* d_ws, size_t ws_size,
                              hipStream_t stream) {
  const float* obs   = (const float*)d_in[0];
  const float* We    = (const float*)d_in[1];
  const float* be    = (const float*)d_in[2];
  const float* Wih_e = (const float*)d_in[3];
  const float* Whh_e = (const float*)d_in[4];
  const float* b_e   = (const float*)d_in[5];
  const float* Wd    = (const float*)d_in[6];
  const float* bd    = (const float*)d_in[7];
  const float* Wih_d = (const float*)d_in[8];
  const float* Whh_d = (const float*)d_in[9];
  const float* b_d   = (const float*)d_in[10];
  const float* Wo    = (const float*)d_in[11];
  const float* bo    = (const float*)d_in[12];
  float* out = (float*)d_out;

  unsigned short* wt_enc = (unsigned short*)d_ws;                 // 128 KB
  unsigned short* wt_dec = wt_enc + NZ * KWT;                     // +128 KB
  unsigned short* xw_enc = wt_dec + NZ * KWT;                     // +32 KB
  float* auxf_dec = (float*)(xw_enc + NZ * XK);                   // +2 KB

  hipLaunchKernelGGL(prep_weights, dim3(2 * NZ), dim3(64), 0, stream,
                     We, be, Wih_e, Whh_e, b_e, Wd, bd, Wih_d, Whh_d, b_d,
                     Wo, bo, wt_enc, wt_dec, xw_enc, auxf_dec);
  hipLaunchKernelGGL(lstm_fused, dim3(BATCH / 64), dim3(512), 0, stream,
                     obs, wt_enc, wt_dec, xw_enc, auxf_dec, Wo, bo, out);
}